// Round 14
// baseline (302.244 us; speedup 1.0000x reference)
//
#include <hip/hip_runtime.h>
#include <math.h>

#define BB 8
#define NN 2048
#define DD 512

typedef _Float16 halfT;
typedef _Float16 half8 __attribute__((ext_vector_type(8)));
typedef _Float16 half4 __attribute__((ext_vector_type(4)));
typedef float f32x4 __attribute__((ext_vector_type(4)));

#define GLOAD16(gp, sp) __builtin_amdgcn_global_load_lds( \
    (const __attribute__((address_space(1))) void*)(gp), \
    (__attribute__((address_space(3))) void*)(sp), 16, 0, 0)

// ---------------------------------------------------------------------------
// W transpose + fp16 split:  WT[e][d] = W[d][e]  ->  (hi, lo) fp16 pairs
// ---------------------------------------------------------------------------
__global__ __launch_bounds__(256) void wsplit_kernel(
    const float* __restrict__ Wq, const float* __restrict__ Wk, const float* __restrict__ Wv,
    _Float16* __restrict__ qhT, _Float16* __restrict__ qlT,
    _Float16* __restrict__ khT, _Float16* __restrict__ klT,
    _Float16* __restrict__ vhT)
{
    __shared__ float t[64][65];
    const int z = blockIdx.z;
    const float* W = (z == 0) ? Wq : ((z == 1) ? Wk : Wv);
    _Float16* Ph = (z == 0) ? qhT : ((z == 1) ? khT : vhT);
    _Float16* Pl = (z == 0) ? qlT : ((z == 1) ? klT : nullptr);
    const int bx = blockIdx.x * 64, by = blockIdx.y * 64;
    const int tid = threadIdx.x;
    #pragma unroll
    for (int i = 0; i < 16; ++i) {
        const int idx = i * 256 + tid;
        const int r = idx >> 6, c = idx & 63;
        t[r][c] = W[(long)(by + r) * 512 + bx + c];
    }
    __syncthreads();
    #pragma unroll
    for (int i = 0; i < 16; ++i) {
        const int idx = i * 256 + tid;
        const int r = idx >> 6, c = idx & 63;
        const float v = t[c][r];
        const _Float16 h = (_Float16)v;
        const long o = (long)(bx + r) * 512 + by + c;
        Ph[o] = h;
        if (z < 2) Pl[o] = (_Float16)(v - (float)h);
    }
}

// ---------------------------------------------------------------------------
// proj v2: 128x128 tile, 256 threads (4 waves, 2x2, 64x64/wave), BK=32,
// single-buffered 32 KB static LDS -> ~4 blocks/CU (cross-block overlap
// hides the per-step drains that stalled the 96 KB/1-block version).
//   z=0: q (3-product split, out hi/lo)  z=1: k (same)  z=2: vT (1-product)
// A (fp32) reg-staged -> cvt/split -> LDS; B pre-split fp16 via gload_lds
// with pre-swizzled source. Involution layout (proven 0-conflict).
// ---------------------------------------------------------------------------
__global__ __launch_bounds__(256) void proj_kernel(
    const float* __restrict__ X0, const float* __restrict__ X1, const float* __restrict__ X2,
    const halfT* __restrict__ B0h, const halfT* __restrict__ B0l,
    const halfT* __restrict__ B1h, const halfT* __restrict__ B1l,
    const halfT* __restrict__ B2h,
    halfT* __restrict__ O0h, halfT* __restrict__ O0l,
    halfT* __restrict__ O1h, halfT* __restrict__ O1l,
    halfT* __restrict__ O2)
{
    // layout (bytes): Ah 0 | Al 8192 | Bh 16384 | Bl 24576   (128 rows x 64 B)
    __shared__ __align__(16) char smem[32768];

    const int tid  = threadIdx.x;
    const int lane = tid & 63;
    const int w    = tid >> 6;            // 0..3
    const int wr   = w >> 1, wc = w & 1;  // wave = 64 x 64

    // bijective XCD swizzle over 1536 blocks (1536 % 8 == 0)
    int h = blockIdx.x;
    h = (h & 7) * 192 + (h >> 3);
    int z, nx, my;
    if (h < 1024) { z = h >> 9; const int r = h & 511; nx = r & 3; my = r >> 2; }
    else          { const int r = h - 1024; z = 2;     nx = r & 3; my = r >> 2; }
    const int bm = my * 128, bn = nx * 128;
    const bool full = (z < 2);

    const float* X = (z == 0) ? X0 : ((z == 1) ? X1 : X2);
    const halfT* Bgh = (z == 0) ? B0h : ((z == 1) ? B1h : B2h);
    const halfT* Bgl = (z == 0) ? B0l : B1l;   // unused when z==2
    halfT* Oh = (z == 0) ? O0h : O1h;
    halfT* Ol = (z == 0) ? O0l : O1l;

    // ---- B staging: 2 passes of 64 rows, gload_lds, pre-swizzled source ----
    const int b_row   = w * 16 + (lane >> 2);            // 0..63 (+64 pass 2)
    const int b_chunk = (lane & 3) ^ ((lane >> 3) & 3);  // = c ^ ((row>>1)&3)
    const long gB0 = (long)(bn + b_row) * DD + b_chunk * 8;
    const long gB1 = (long)(bn + b_row + 64) * DD + b_chunk * 8;
    const int ldstB = w * 1024;

    // ---- A staging: row = tid>>1 (0..127), granules g0,g0+1 of 4 ----
    const int a_row = tid >> 1;
    const int g0    = (tid & 1) << 1;
    const int aswz  = (a_row >> 1) & 3;
    const int p0 = g0 ^ aswz, p1 = (g0 + 1) ^ aswz;
    const long gA = (long)(bm + a_row) * DD + g0 * 8;    // 16 consecutive floats
    const int aOff0 = a_row * 64 + p0 * 16;
    const int aOff1 = a_row * 64 + p1 * 16;

    float ar[16];
    auto loadA = [&](int t) {
        const long kk = (long)t * 32;
        *(float4*)&ar[0]  = *(const float4*)(X + gA + kk);
        *(float4*)&ar[4]  = *(const float4*)(X + gA + kk + 4);
        *(float4*)&ar[8]  = *(const float4*)(X + gA + kk + 8);
        *(float4*)&ar[12] = *(const float4*)(X + gA + kk + 12);
    };
    auto stageB = [&](int t) {
        const long kk = (long)t * 32;
        GLOAD16(Bgh + gB0 + kk, smem + 16384 + ldstB);
        GLOAD16(Bgh + gB1 + kk, smem + 16384 + 4096 + ldstB);
        if (full) {
            GLOAD16(Bgl + gB0 + kk, smem + 24576 + ldstB);
            GLOAD16(Bgl + gB1 + kk, smem + 24576 + 4096 + ldstB);
        }
    };
    auto writeA = [&]() {
        half8 h0, h1;
        #pragma unroll
        for (int i = 0; i < 8; ++i) h0[i] = (_Float16)ar[i];
        #pragma unroll
        for (int i = 0; i < 8; ++i) h1[i] = (_Float16)ar[8 + i];
        *(half8*)(smem + aOff0) = h0;
        *(half8*)(smem + aOff1) = h1;
        if (full) {
            half8 l0, l1;
            #pragma unroll
            for (int i = 0; i < 8; ++i) l0[i] = (_Float16)(ar[i] - (float)h0[i]);
            #pragma unroll
            for (int i = 0; i < 8; ++i) l1[i] = (_Float16)(ar[8 + i] - (float)h1[i]);
            *(half8*)(smem + 8192 + aOff0) = l0;
            *(half8*)(smem + 8192 + aOff1) = l1;
        }
    };

    // fragment read offsets (involution, proven conflict-free)
    const int lr  = lane & 15;
    const int q16 = lane >> 4;
    const int frag = lr * 64 + ((q16 ^ ((lr >> 1) & 3)) << 4);
    const int abase = wr * 4096 + frag;   // + m*1024
    const int bbase = wc * 4096 + frag;   // + j*1024

    f32x4 acc[4][4];
    #pragma unroll
    for (int i = 0; i < 4; ++i)
        #pragma unroll
        for (int j = 0; j < 4; ++j) acc[i][j] = (f32x4)0.0f;

    loadA(0);

    for (int t = 0; t < 16; ++t) {
        writeA();                       // tile t A -> LDS
        stageB(t);                      // tile t B -> LDS (async)
        if (t < 15) loadA(t + 1);       // next A flies across this step
        __syncthreads();

        half8 ah[4], bh[4];
        #pragma unroll
        for (int m = 0; m < 4; ++m)
            ah[m] = *(const half8*)(smem + abase + m * 1024);
        #pragma unroll
        for (int j = 0; j < 4; ++j)
            bh[j] = *(const half8*)(smem + 16384 + bbase + j * 1024);
        __builtin_amdgcn_s_setprio(1);
        #pragma unroll
        for (int m = 0; m < 4; ++m)
            #pragma unroll
            for (int j = 0; j < 4; ++j)
                acc[m][j] = __builtin_amdgcn_mfma_f32_16x16x32_f16(ah[m], bh[j], acc[m][j], 0, 0, 0);
        __builtin_amdgcn_s_setprio(0);

        if (full) {
            half8 bl[4];
            #pragma unroll
            for (int j = 0; j < 4; ++j)
                bl[j] = *(const half8*)(smem + 24576 + bbase + j * 1024);
            __builtin_amdgcn_s_setprio(1);
            #pragma unroll
            for (int m = 0; m < 4; ++m)
                #pragma unroll
                for (int j = 0; j < 4; ++j)
                    acc[m][j] = __builtin_amdgcn_mfma_f32_16x16x32_f16(ah[m], bl[j], acc[m][j], 0, 0, 0);
            __builtin_amdgcn_s_setprio(0);

            __builtin_amdgcn_s_setprio(1);
            #pragma unroll
            for (int m = 0; m < 4; ++m) {
                const half8 al = *(const half8*)(smem + 8192 + abase + m * 1024);
                #pragma unroll
                for (int j = 0; j < 4; ++j)
                    acc[m][j] = __builtin_amdgcn_mfma_f32_16x16x32_f16(al, bh[j], acc[m][j], 0, 0, 0);
            }
            __builtin_amdgcn_s_setprio(0);
        }
        __syncthreads();
    }

    // epilogue
    if (full) {
        #pragma unroll
        for (int m = 0; m < 4; ++m) {
            const int rb = bm + wr * 64 + m * 16 + (q16 << 2);
            #pragma unroll
            for (int j = 0; j < 4; ++j) {
                const int gc = bn + wc * 64 + j * 16 + lr;
                #pragma unroll
                for (int r = 0; r < 4; ++r) {
                    const float vv = acc[m][j][r];
                    const _Float16 hh = (_Float16)vv;
                    const long o = (long)(rb + r) * DD + gc;
                    Oh[o] = hh;
                    Ol[o] = (_Float16)(vv - (float)hh);
                }
            }
        }
    } else {
        #pragma unroll
        for (int m = 0; m < 4; ++m) {
            const int rb = bm + wr * 64 + m * 16 + (q16 << 2);
            #pragma unroll
            for (int j = 0; j < 4; ++j) {
                const int gc = bn + wc * 64 + j * 16 + lr;
                half4 hv;
                #pragma unroll
                for (int r = 0; r < 4; ++r) hv[r] = (_Float16)acc[m][j][r];
                const int b = rb >> 11, rIn = rb & 2047;
                *(half4*)&O2[((long)b * 512 + gc) * 2048 + rIn] = hv;
            }
        }
    }
}

// ---------------------------------------------------------------------------
// scores256 v2 (proven 120us, 0 conflicts): 256x256 tile, 8 waves (2x4),
// BK=32, 3-product split, gload_lds dbuf with pre-swizzled source, 2-phase.
// ---------------------------------------------------------------------------
__global__ __launch_bounds__(512, 2) void scores256_kernel(
    const halfT* __restrict__ qh, const halfT* __restrict__ ql,
    const halfT* __restrict__ kh, const halfT* __restrict__ kl,
    float* __restrict__ C, const float* __restrict__ si, float scale)
{
    extern __shared__ __align__(16) char smem[];   // 2 bufs x 65536 B
    // buf layout: Ah 0 | Al 16384 | Bh 32768 | Bl 49152

    const int tid  = threadIdx.x;
    const int lane = tid & 63;
    const int w    = tid >> 6;
    const int wr   = w >> 2, wc = w & 3;  // per-wave output 128 x 64

    int flat = (blockIdx.z << 6) | (blockIdx.y << 3) | blockIdx.x;
    flat = ((flat & 7) << 6) | (flat >> 3);
    const int bx = flat & 7, by = (flat >> 3) & 7, bz = flat >> 6;
    const int bm = by * 256, bn = bx * 256;

    const long zoff = (long)bz * NN * DD;
    const halfT* A_h = qh + zoff;
    const halfT* A_l = ql + zoff;
    const halfT* B_h = kh + zoff;
    const halfT* B_l = kl + zoff;

    const int s_row   = w * 16 + (lane >> 2);
    const int s_chunk = (lane & 3) ^ ((lane >> 3) & 3);
    const long gA = (long)(bm + s_row) * DD + s_chunk * 8;
    const long gB = (long)(bn + s_row) * DD + s_chunk * 8;
    const int ldst = w * 1024;
    const long rstep = (long)128 * DD;

    auto stage = [&](char* buf, int t) {
        const long kk = (long)t * 32;
        GLOAD16(A_h + gA + kk,         buf + ldst);
        GLOAD16(A_h + gA + rstep + kk, buf + 8192 + ldst);
        GLOAD16(A_l + gA + kk,         buf + 16384 + ldst);
        GLOAD16(A_l + gA + rstep + kk, buf + 16384 + 8192 + ldst);
        GLOAD16(B_h + gB + kk,         buf + 32768 + ldst);
        GLOAD16(B_h + gB + rstep + kk, buf + 32768 + 8192 + ldst);
        GLOAD16(B_l + gB + kk,         buf + 49152 + ldst);
        GLOAD16(B_l + gB + rstep + kk, buf + 49152 + 8192 + ldst);
    };

    const int lr   = lane & 15;
    const int q16  = lane >> 4;
    const int fswz = (lr >> 1) & 3;
    const int frag = lr * 64 + ((q16 ^ fswz) << 4);
    const int abase = wr * 8192 + frag;
    const int bbase = wc * 4096 + frag;

    f32x4 acc[8][4];
    #pragma unroll
    for (int m = 0; m < 8; ++m)
        #pragma unroll
        for (int n = 0; n < 4; ++n) acc[m][n] = (f32x4)0.0f;

    stage(smem, 0);
    asm volatile("s_waitcnt vmcnt(0)" ::: "memory");
    __builtin_amdgcn_s_barrier();

    for (int t = 0; t < 16; ++t) {
        char* cur = smem + (size_t)(t & 1) * 65536;
        char* nxt = smem + (size_t)((t + 1) & 1) * 65536;

        if (t < 15) stage(nxt, t + 1);

        half8 ah[8], bh[4], bl[4];
        #pragma unroll
        for (int n = 0; n < 4; ++n)
            bh[n] = *(const half8*)(cur + 32768 + bbase + n * 1024);
        #pragma unroll
        for (int m = 0; m < 8; ++m)
            ah[m] = *(const half8*)(cur + abase + m * 1024);
        __builtin_amdgcn_s_setprio(1);
        #pragma unroll
        for (int m = 0; m < 8; ++m)
            #pragma unroll
            for (int n = 0; n < 4; ++n)
                acc[m][n] = __builtin_amdgcn_mfma_f32_16x16x32_f16(ah[m], bh[n], acc[m][n], 0, 0, 0);
        __builtin_amdgcn_s_setprio(0);

        #pragma unroll
        for (int n = 0; n < 4; ++n)
            bl[n] = *(const half8*)(cur + 49152 + bbase + n * 1024);
        __builtin_amdgcn_s_setprio(1);
        #pragma unroll
        for (int m = 0; m < 8; ++m)
            #pragma unroll
            for (int n = 0; n < 4; ++n)
                acc[m][n] = __builtin_amdgcn_mfma_f32_16x16x32_f16(ah[m], bl[n], acc[m][n], 0, 0, 0);
        __builtin_amdgcn_s_setprio(0);

        __builtin_amdgcn_s_setprio(1);
        #pragma unroll
        for (int m = 0; m < 8; ++m) {
            const half8 al = *(const half8*)(cur + 16384 + abase + m * 1024);
            #pragma unroll
            for (int n = 0; n < 4; ++n)
                acc[m][n] = __builtin_amdgcn_mfma_f32_16x16x32_f16(al, bh[n], acc[m][n], 0, 0, 0);
        }
        __builtin_amdgcn_s_setprio(0);

        if (t < 15) {
            asm volatile("s_waitcnt vmcnt(0)" ::: "memory");
            __builtin_amdgcn_s_barrier();
        }
    }

    float* Cz = C + (long)bz * NN * NN;
    #pragma unroll
    for (int m = 0; m < 8; ++m) {
        const int rb = bm + wr * 128 + m * 16 + ((lane >> 4) << 2);
        #pragma unroll
        for (int n = 0; n < 4; ++n) {
            const int gc = bn + wc * 64 + n * 16 + (lane & 15);
            #pragma unroll
            for (int r = 0; r < 4; ++r) {
                const int gr = rb + r;
                float vv = acc[m][n][r] * scale;
                if (gr == gc) vv += fminf(expf(si[gr]), 3.0f);
                Cz[(long)gr * NN + gc] = vv;
            }
        }
    }
}

// ---------------------------------------------------------------------------
// AV GEMM: 256x128 tile, 8 waves (4x2, 64x64/wave), 16x16 MFMA, K=2048,
// 3-deep buffer ring (3 x 24KB) with counted vmcnt(3) (T4).
// ---------------------------------------------------------------------------
__global__ __launch_bounds__(512, 2) void av_kernel(
    const halfT* __restrict__ P, const halfT* __restrict__ V,
    float* __restrict__ O)
{
    extern __shared__ __align__(16) char smem[];   // 3 bufs x 24576 B

    const int tid  = threadIdx.x;
    const int lane = tid & 63;
    const int w    = tid >> 6;
    const int wr   = w >> 1, wc = w & 1;

    int flat = blockIdx.x;                       // 0..255
    flat = ((flat & 7) << 5) | (flat >> 3);      // batch bz on XCD bz
    const int nx = flat & 3, my = (flat >> 2) & 7, bz = flat >> 5;
    const int bm = my * 256, bn = nx * 128;

    const halfT* A = P + (long)bz * NN * NN;
    const halfT* B = V + (long)bz * DD * NN;

    const int s_row   = w * 16 + (lane >> 2);
    const int s_chunk = (lane & 3) ^ ((lane >> 3) & 3);
    const long gA = (long)(bm + s_row) * NN + s_chunk * 8;
    const long gB = (long)(bn + s_row) * NN + s_chunk * 8;
    const int ldst = w * 1024;
    const long rstep = (long)128 * NN;

    auto stage = [&](char* buf, int t) {
        const long kk = (long)t * 32;
        GLOAD16(A + gA + kk,         buf + ldst);
        GLOAD16(A + gA + rstep + kk, buf + 8192 + ldst);
        GLOAD16(B + gB + kk,         buf + 16384 + ldst);
    };

    const int lr  = lane & 15;
    const int q16 = lane >> 4;
    const int frag = lr * 64 + ((q16 ^ ((lr >> 1) & 3)) << 4);
    const int abase = wr * 4096 + frag;
    const int bbase = wc * 4096 + frag;

    f32x4 acc[4][4];
    #pragma unroll
    for (int m = 0; m < 4; ++m)
        #pragma unroll
        for (int j = 0; j < 4; ++j) acc[m][j] = (f32x4)0.0f;

    stage(smem, 0);
    stage(smem + 24576, 1);
    asm volatile("s_waitcnt vmcnt(3)" ::: "memory");
    __builtin_amdgcn_s_barrier();
    __builtin_amdgcn_sched_barrier(0);

    int cb = 0;
    for (int t = 0; t < 64; ++t) {
        char* cur = smem + (size_t)cb * 24576;
        const int nb = (cb + 2 >= 3) ? cb - 1 : cb + 2;
        if (t < 62) stage(smem + (size_t)nb * 24576, t + 2);

        half8 ah[4], bh[4];
        #pragma unroll
        for (int m = 0; m < 4; ++m)
            ah[m] = *(const half8*)(cur + abase + m * 1024);
        #pragma unroll
        for (int j = 0; j < 4; ++j)
            bh[j] = *(const half8*)(cur + 16384 + bbase + j * 1024);
        __builtin_amdgcn_s_setprio(1);
        #pragma unroll
        for (int m = 0; m < 4; ++m)
            #pragma unroll
            for (int j = 0; j < 4; ++j)
                acc[m][j] = __builtin_amdgcn_mfma_f32_16x16x32_f16(ah[m], bh[j], acc[m][j], 0, 0, 0);
        __builtin_amdgcn_s_setprio(0);

        if (t < 63) {
            if (t < 62) { asm volatile("s_waitcnt vmcnt(3)" ::: "memory"); }
            else        { asm volatile("s_waitcnt vmcnt(0)" ::: "memory"); }
            __builtin_amdgcn_s_barrier();
            __builtin_amdgcn_sched_barrier(0);
        }
        cb = (cb + 1 == 3) ? 0 : cb + 1;
    }

    float* Oz = O + (long)bz * NN * DD;
    #pragma unroll
    for (int m = 0; m < 4; ++m) {
        const int rb = bm + wr * 64 + m * 16 + (q16 << 2);
        #pragma unroll
        for (int j = 0; j < 4; ++j) {
            const int gc = bn + wc * 64 + j * 16 + lr;
            #pragma unroll
            for (int r = 0; r < 4; ++r)
                Oz[(long)(rb + r) * DD + gc] = acc[m][j][r];
        }
    }
}

// ---------------------------------------------------------------------------
// In-place row softmax + entropy partial + fp16 copy of attn.
// ---------------------------------------------------------------------------
__global__ __launch_bounds__(256) void softmax_entropy_kernel(
    float* __restrict__ attn, _Float16* __restrict__ ah, float* __restrict__ partials)
{
    __shared__ float red[4];
    const long row = blockIdx.x;
    float* p = attn + row * (long)NN;
    _Float16* ph = ah + row * (long)NN;
    const int tid = threadIdx.x;
    const int base = tid * 8;

    float4 va = *(const float4*)(p + base);
    float4 vb = *(const float4*)(p + base + 4);
    float v[8] = {va.x, va.y, va.z, va.w, vb.x, vb.y, vb.z, vb.w};

    float m = v[0];
    #pragma unroll
    for (int i = 1; i < 8; ++i) m = fmaxf(m, v[i]);
    #pragma unroll
    for (int o = 32; o; o >>= 1) m = fmaxf(m, __shfl_xor(m, o, 64));
    if ((tid & 63) == 0) red[tid >> 6] = m;
    __syncthreads();
    m = fmaxf(fmaxf(red[0], red[1]), fmaxf(red[2], red[3]));

    float t[8];
    float s = 0.f;
    #pragma unroll
    for (int i = 0; i < 8; ++i) { t[i] = v[i] - m; v[i] = expf(t[i]); s += v[i]; }
    #pragma unroll
    for (int o = 32; o; o >>= 1) s += __shfl_xor(s, o, 64);
    __syncthreads();
    if ((tid & 63) == 0) red[tid >> 6] = s;
    __syncthreads();
    s = red[0] + red[1] + red[2] + red[3];

    const float inv = 1.0f / s;
    const float lns = logf(s);
    float e = 0.f;
    float pv[8];
    #pragma unroll
    for (int i = 0; i < 8; ++i) {
        pv[i] = v[i] * inv;
        e = fmaf(pv[i], t[i] - lns, e);
    }
    *(float4*)(p + base)     = make_float4(pv[0], pv[1], pv[2], pv[3]);
    *(float4*)(p + base + 4) = make_float4(pv[4], pv[5], pv[6], pv[7]);
    half8 h;
    #pragma unroll
    for (int i = 0; i < 8; ++i) h[i] = (_Float16)pv[i];
    *(half8*)(ph + base) = h;

    #pragma unroll
    for (int o = 32; o; o >>= 1) e += __shfl_xor(e, o, 64);
    __syncthreads();
    if ((tid & 63) == 0) red[tid >> 6] = e;
    __syncthreads();
    if (tid == 0) partials[row] = red[0] + red[1] + red[2] + red[3];
}

__global__ __launch_bounds__(256) void ent_reduce_kernel(
    const float* __restrict__ partials, float* __restrict__ ent)
{
    __shared__ float red[4];
    float s = 0.f;
    for (int i = threadIdx.x; i < BB * NN; i += 256) s += partials[i];
    #pragma unroll
    for (int o = 32; o; o >>= 1) s += __shfl_xor(s, o, 64);
    if ((threadIdx.x & 63) == 0) red[threadIdx.x >> 6] = s;
    __syncthreads();
    if (threadIdx.x == 0)
        *ent = -(red[0] + red[1] + red[2] + red[3]) / (float)(BB * NN);
}

extern "C" void kernel_launch(void* const* d_in, const int* in_sizes, int n_in,
                              void* d_out, int out_size, void* d_ws, size_t ws_size,
                              hipStream_t stream) {
    const float* query = (const float*)d_in[0];
    const float* key   = (const float*)d_in[1];
    const float* value = (const float*)d_in[2];
    const float* Wq    = (const float*)d_in[3];
    const float* Wk    = (const float*)d_in[4];
    const float* Wv    = (const float*)d_in[5];
    const float* si    = (const float*)d_in[6];

    float* out  = (float*)d_out;                        // [B,N,D]
    float* attn = out + (size_t)BB * NN * DD;           // [B,N,N]
    float* ent  = attn + (size_t)BB * NN * NN;          // scalar

    const size_t NK = (size_t)BB * NN * DD;             // 8.39M elements
    _Float16* ws16 = (_Float16*)d_ws;
    _Float16* qh = ws16;            // 16.8 MB each
    _Float16* ql = qh + NK;
    _Float16* kh = ql + NK;
    _Float16* kl = kh + NK;
    _Float16* vT = kl + NK;         // vT fp16 [b][512][2048]
    _Float16* WqhT = vT + NK;       // 0.5 MB each
    _Float16* WqlT = WqhT + DD * DD;
    _Float16* WkhT = WqlT + DD * DD;
    _Float16* WklT = WkhT + DD * DD;
    _Float16* WvhT = WklT + DD * DD;
    float* partials = (float*)(WvhT + DD * DD);         // 64 KB
    _Float16* attn_h = ws16;        // 67 MB, aliases qh..kl (dead after scores)

    const dim3 blk(256);
    const float inv_sqrt_d = 0.044194173824159216f;     // 1/sqrt(512)

    wsplit_kernel<<<dim3(8, 8, 3), blk, 0, stream>>>(Wq, Wk, Wv,
        WqhT, WqlT, WkhT, WklT, WvhT);

    // merged q/k/v projections: 1536 blocks x 256 threads, 32 KB static LDS
    proj_kernel<<<dim3(1536), blk, 0, stream>>>(
        query, key, value, WqhT, WqlT, WkhT, WklT, WvhT,
        qh, ql, kh, kl, vT);

    // scores = q k^T / sqrt(d) + diag(min(exp(si),3))  [v2 proven]
    scores256_kernel<<<dim3(8, 8, 8), dim3(512), 131072, stream>>>(
        qh, ql, kh, kl, attn, si, inv_sqrt_d);

    softmax_entropy_kernel<<<dim3(BB * NN), blk, 0, stream>>>(attn, attn_h, partials);
    ent_reduce_kernel<<<dim3(1), blk, 0, stream>>>(partials, ent);

    // out = attn @ v  [3-buf counted ring]
    av_kernel<<<dim3(256), dim3(512), 73728, stream>>>(attn_h, vT, out);
}

// Round 15
// 292.241 us; speedup vs baseline: 1.0342x; 1.0342x over previous
//
#include <hip/hip_runtime.h>
#include <math.h>

#define BB 8
#define NN 2048
#define DD 512

typedef _Float16 halfT;
typedef _Float16 half8 __attribute__((ext_vector_type(8)));
typedef _Float16 half4 __attribute__((ext_vector_type(4)));
typedef float f32x4 __attribute__((ext_vector_type(4)));

#define GLOAD16(gp, sp) __builtin_amdgcn_global_load_lds( \
    (const __attribute__((address_space(1))) void*)(gp), \
    (__attribute__((address_space(3))) void*)(sp), 16, 0, 0)

// ---------------------------------------------------------------------------
// W transpose + fp16 split:  WT[e][d] = W[d][e]  ->  (hi, lo) fp16 pairs
// ---------------------------------------------------------------------------
__global__ __launch_bounds__(256) void wsplit_kernel(
    const float* __restrict__ Wq, const float* __restrict__ Wk, const float* __restrict__ Wv,
    _Float16* __restrict__ qhT, _Float16* __restrict__ qlT,
    _Float16* __restrict__ khT, _Float16* __restrict__ klT,
    _Float16* __restrict__ vhT)
{
    __shared__ float t[64][65];
    const int z = blockIdx.z;
    const float* W = (z == 0) ? Wq : ((z == 1) ? Wk : Wv);
    _Float16* Ph = (z == 0) ? qhT : ((z == 1) ? khT : vhT);
    _Float16* Pl = (z == 0) ? qlT : ((z == 1) ? klT : nullptr);
    const int bx = blockIdx.x * 64, by = blockIdx.y * 64;
    const int tid = threadIdx.x;
    #pragma unroll
    for (int i = 0; i < 16; ++i) {
        const int idx = i * 256 + tid;
        const int r = idx >> 6, c = idx & 63;
        t[r][c] = W[(long)(by + r) * 512 + bx + c];
    }
    __syncthreads();
    #pragma unroll
    for (int i = 0; i < 16; ++i) {
        const int idx = i * 256 + tid;
        const int r = idx >> 6, c = idx & 63;
        const float v = t[c][r];
        const _Float16 h = (_Float16)v;
        const long o = (long)(bx + r) * 512 + by + c;
        Ph[o] = h;
        if (z < 2) Pl[o] = (_Float16)(v - (float)h);
    }
}

// ---------------------------------------------------------------------------
// Unified projection kernel: 256x128 tile, 8 waves, BK=32.
//   z=0: q (3-product split, out hi/lo) z=1: k (same) z=2: vT (1-product)
// ---------------------------------------------------------------------------
__global__ __launch_bounds__(512, 2) void proj_kernel(
    const float* __restrict__ X0, const float* __restrict__ X1, const float* __restrict__ X2,
    const halfT* __restrict__ B0h, const halfT* __restrict__ B0l,
    const halfT* __restrict__ B1h, const halfT* __restrict__ B1l,
    const halfT* __restrict__ B2h,
    halfT* __restrict__ O0h, halfT* __restrict__ O0l,
    halfT* __restrict__ O1h, halfT* __restrict__ O1l,
    halfT* __restrict__ O2)
{
    extern __shared__ __align__(16) char smem[];   // 2 bufs x 49152 B
    // buf layout: Ah 0 | Al 16384 | Bh 32768 | Bl 40960

    const int tid  = threadIdx.x;
    const int lane = tid & 63;
    const int w    = tid >> 6;
    const int wr   = w >> 1, wc = w & 1;   // wave = 64 rows x 64 cols

    const int h = blockIdx.x;              // 0..767
    int z, nx, my;
    if (h < 512) {
        const int L = ((h & 7) << 6) | (h >> 3);
        z = L >> 8; nx = L & 3; my = (L >> 2) & 63;
    } else {
        const int hv = h - 512;            // 0..255
        const int L = ((hv & 7) << 5) | (hv >> 3);
        z = 2; nx = L & 3; my = L >> 2;
    }
    const int bm = my * 256, bn = nx * 128;
    const bool full = (z < 2);

    const float* X = (z == 0) ? X0 : ((z == 1) ? X1 : X2);
    const halfT* Bgh = (z == 0) ? B0h : ((z == 1) ? B1h : B2h);
    const halfT* Bgl = (z == 0) ? B0l : B1l;   // unused when z==2
    halfT* Oh = (z == 0) ? O0h : O1h;
    halfT* Ol = (z == 0) ? O0l : O1l;

    const int b_row   = w * 16 + (lane >> 2);
    const int b_chunk = (lane & 3) ^ ((lane >> 3) & 3);
    const long gB = (long)(bn + b_row) * DD + b_chunk * 8;
    const int ldstB = w * 1024;

    const int a_row0 = tid >> 2;
    const int a_gc   = tid & 3;
    const int a_phys = a_gc ^ ((a_row0 >> 1) & 3);
    const long gA0 = (long)(bm + a_row0) * DD + a_gc * 8;
    const long gA1 = (long)(bm + a_row0 + 128) * DD + a_gc * 8;
    const int aOff0 = a_row0 * 64 + a_phys * 16;
    const int aOff1 = (a_row0 + 128) * 64 + a_phys * 16;

    float ar[16];
    auto loadA = [&](int t) {
        const long kk = (long)t * 32;
        *(float4*)&ar[0]  = *(const float4*)(X + gA0 + kk);
        *(float4*)&ar[4]  = *(const float4*)(X + gA0 + kk + 4);
        *(float4*)&ar[8]  = *(const float4*)(X + gA1 + kk);
        *(float4*)&ar[12] = *(const float4*)(X + gA1 + kk + 4);
    };
    auto stageB = [&](char* buf, int t) {
        const long kk = (long)t * 32;
        GLOAD16(Bgh + gB + kk, buf + 32768 + ldstB);
        if (full) GLOAD16(Bgl + gB + kk, buf + 40960 + ldstB);
    };
    auto writeA = [&](char* buf) {
        half8 h0, l0, h1, l1;
        #pragma unroll
        for (int i = 0; i < 8; ++i) {
            const _Float16 hh = (_Float16)ar[i];
            h0[i] = hh; l0[i] = (_Float16)(ar[i] - (float)hh);
        }
        #pragma unroll
        for (int i = 0; i < 8; ++i) {
            const _Float16 hh = (_Float16)ar[8 + i];
            h1[i] = hh; l1[i] = (_Float16)(ar[8 + i] - (float)hh);
        }
        *(half8*)(buf + aOff0) = h0;
        *(half8*)(buf + aOff1) = h1;
        if (full) {
            *(half8*)(buf + 16384 + aOff0) = l0;
            *(half8*)(buf + 16384 + aOff1) = l1;
        }
    };

    const int lr  = lane & 15;
    const int q16 = lane >> 4;
    const int frag = lr * 64 + ((q16 ^ ((lr >> 1) & 3)) << 4);
    const int abase = wr * 4096 + frag;
    const int bbase = wc * 4096 + frag;

    f32x4 acc[4][4];
    #pragma unroll
    for (int i = 0; i < 4; ++i)
        #pragma unroll
        for (int j = 0; j < 4; ++j) acc[i][j] = (f32x4)0.0f;

    loadA(0);
    stageB(smem, 0);
    writeA(smem);
    asm volatile("s_waitcnt vmcnt(0) lgkmcnt(0)" ::: "memory");
    __builtin_amdgcn_s_barrier();
    __builtin_amdgcn_sched_barrier(0);

    for (int t = 0; t < 16; ++t) {
        char* cur = smem + (size_t)(t & 1) * 49152;
        char* nxt = smem + (size_t)((t + 1) & 1) * 49152;
        const bool pf = (t < 15);

        if (pf) { loadA(t + 1); stageB(nxt, t + 1); }

        half8 ah[4], bh[4], bl[4];
        #pragma unroll
        for (int m = 0; m < 4; ++m)
            ah[m] = *(const half8*)(cur + abase + m * 1024);
        #pragma unroll
        for (int j = 0; j < 4; ++j)
            bh[j] = *(const half8*)(cur + 32768 + bbase + j * 1024);
        __builtin_amdgcn_s_setprio(1);
        #pragma unroll
        for (int m = 0; m < 4; ++m)
            #pragma unroll
            for (int j = 0; j < 4; ++j)
                acc[m][j] = __builtin_amdgcn_mfma_f32_16x16x32_f16(ah[m], bh[j], acc[m][j], 0, 0, 0);
        __builtin_amdgcn_s_setprio(0);

        if (full) {
            #pragma unroll
            for (int j = 0; j < 4; ++j)
                bl[j] = *(const half8*)(cur + 40960 + bbase + j * 1024);
            __builtin_amdgcn_s_setprio(1);
            #pragma unroll
            for (int m = 0; m < 4; ++m)
                #pragma unroll
                for (int j = 0; j < 4; ++j)
                    acc[m][j] = __builtin_amdgcn_mfma_f32_16x16x32_f16(ah[m], bl[j], acc[m][j], 0, 0, 0);
            __builtin_amdgcn_s_setprio(0);

            __builtin_amdgcn_s_setprio(1);
            #pragma unroll
            for (int m = 0; m < 4; ++m) {
                const half8 al = *(const half8*)(cur + 16384 + abase + m * 1024);
                #pragma unroll
                for (int j = 0; j < 4; ++j)
                    acc[m][j] = __builtin_amdgcn_mfma_f32_16x16x32_f16(al, bh[j], acc[m][j], 0, 0, 0);
            }
            __builtin_amdgcn_s_setprio(0);
        }

        if (pf) writeA(nxt);
        asm volatile("s_waitcnt vmcnt(0) lgkmcnt(0)" ::: "memory");
        __builtin_amdgcn_s_barrier();
        __builtin_amdgcn_sched_barrier(0);
    }

    // epilogue
    if (full) {
        #pragma unroll
        for (int m = 0; m < 4; ++m) {
            const int rb = bm + wr * 64 + m * 16 + (q16 << 2);
            #pragma unroll
            for (int j = 0; j < 4; ++j) {
                const int gc = bn + wc * 64 + j * 16 + lr;
                #pragma unroll
                for (int r = 0; r < 4; ++r) {
                    const float vv = acc[m][j][r];
                    const _Float16 hh = (_Float16)vv;
                    const long o = (long)(rb + r) * DD + gc;
                    Oh[o] = hh;
                    Ol[o] = (_Float16)(vv - (float)hh);
                }
            }
        }
    } else {
        #pragma unroll
        for (int m = 0; m < 4; ++m) {
            const int rb = bm + wr * 64 + m * 16 + (q16 << 2);
            #pragma unroll
            for (int j = 0; j < 4; ++j) {
                const int gc = bn + wc * 64 + j * 16 + lr;
                half4 hv;
                #pragma unroll
                for (int r = 0; r < 4; ++r) hv[r] = (_Float16)acc[m][j][r];
                const int b = rb >> 11, rIn = rb & 2047;
                *(half4*)&O2[((long)b * 512 + gc) * 2048 + rIn] = hv;
            }
        }
    }
}

// ---------------------------------------------------------------------------
// scores256 v2 (proven 120us, 0 conflicts): 256x256 tile, 8 waves (2x4),
// BK=32, 3-product split, gload_lds dbuf with pre-swizzled source, 2-phase.
// ---------------------------------------------------------------------------
__global__ __launch_bounds__(512, 2) void scores256_kernel(
    const halfT* __restrict__ qh, const halfT* __restrict__ ql,
    const halfT* __restrict__ kh, const halfT* __restrict__ kl,
    float* __restrict__ C, const float* __restrict__ si, float scale)
{
    extern __shared__ __align__(16) char smem[];   // 2 bufs x 65536 B
    // buf layout: Ah 0 | Al 16384 | Bh 32768 | Bl 49152

    const int tid  = threadIdx.x;
    const int lane = tid & 63;
    const int w    = tid >> 6;
    const int wr   = w >> 2, wc = w & 3;  // per-wave output 128 x 64

    int flat = (blockIdx.z << 6) | (blockIdx.y << 3) | blockIdx.x;
    flat = ((flat & 7) << 6) | (flat >> 3);
    const int bx = flat & 7, by = (flat >> 3) & 7, bz = flat >> 6;
    const int bm = by * 256, bn = bx * 256;

    const long zoff = (long)bz * NN * DD;
    const halfT* A_h = qh + zoff;
    const halfT* A_l = ql + zoff;
    const halfT* B_h = kh + zoff;
    const halfT* B_l = kl + zoff;

    const int s_row   = w * 16 + (lane >> 2);
    const int s_chunk = (lane & 3) ^ ((lane >> 3) & 3);
    const long gA = (long)(bm + s_row) * DD + s_chunk * 8;
    const long gB = (long)(bn + s_row) * DD + s_chunk * 8;
    const int ldst = w * 1024;
    const long rstep = (long)128 * DD;

    auto stage = [&](char* buf, int t) {
        const long kk = (long)t * 32;
        GLOAD16(A_h + gA + kk,         buf + ldst);
        GLOAD16(A_h + gA + rstep + kk, buf + 8192 + ldst);
        GLOAD16(A_l + gA + kk,         buf + 16384 + ldst);
        GLOAD16(A_l + gA + rstep + kk, buf + 16384 + 8192 + ldst);
        GLOAD16(B_h + gB + kk,         buf + 32768 + ldst);
        GLOAD16(B_h + gB + rstep + kk, buf + 32768 + 8192 + ldst);
        GLOAD16(B_l + gB + kk,         buf + 49152 + ldst);
        GLOAD16(B_l + gB + rstep + kk, buf + 49152 + 8192 + ldst);
    };

    const int lr   = lane & 15;
    const int q16  = lane >> 4;
    const int fswz = (lr >> 1) & 3;
    const int frag = lr * 64 + ((q16 ^ fswz) << 4);
    const int abase = wr * 8192 + frag;
    const int bbase = wc * 4096 + frag;

    f32x4 acc[8][4];
    #pragma unroll
    for (int m = 0; m < 8; ++m)
        #pragma unroll
        for (int n = 0; n < 4; ++n) acc[m][n] = (f32x4)0.0f;

    stage(smem, 0);
    asm volatile("s_waitcnt vmcnt(0)" ::: "memory");
    __builtin_amdgcn_s_barrier();

    for (int t = 0; t < 16; ++t) {
        char* cur = smem + (size_t)(t & 1) * 65536;
        char* nxt = smem + (size_t)((t + 1) & 1) * 65536;

        if (t < 15) stage(nxt, t + 1);

        half8 ah[8], bh[4], bl[4];
        #pragma unroll
        for (int n = 0; n < 4; ++n)
            bh[n] = *(const half8*)(cur + 32768 + bbase + n * 1024);
        #pragma unroll
        for (int m = 0; m < 8; ++m)
            ah[m] = *(const half8*)(cur + abase + m * 1024);
        __builtin_amdgcn_s_setprio(1);
        #pragma unroll
        for (int m = 0; m < 8; ++m)
            #pragma unroll
            for (int n = 0; n < 4; ++n)
                acc[m][n] = __builtin_amdgcn_mfma_f32_16x16x32_f16(ah[m], bh[n], acc[m][n], 0, 0, 0);
        __builtin_amdgcn_s_setprio(0);

        #pragma unroll
        for (int n = 0; n < 4; ++n)
            bl[n] = *(const half8*)(cur + 49152 + bbase + n * 1024);
        __builtin_amdgcn_s_setprio(1);
        #pragma unroll
        for (int m = 0; m < 8; ++m)
            #pragma unroll
            for (int n = 0; n < 4; ++n)
                acc[m][n] = __builtin_amdgcn_mfma_f32_16x16x32_f16(ah[m], bl[n], acc[m][n], 0, 0, 0);
        __builtin_amdgcn_s_setprio(0);

        __builtin_amdgcn_s_setprio(1);
        #pragma unroll
        for (int m = 0; m < 8; ++m) {
            const half8 al = *(const half8*)(cur + 16384 + abase + m * 1024);
            #pragma unroll
            for (int n = 0; n < 4; ++n)
                acc[m][n] = __builtin_amdgcn_mfma_f32_16x16x32_f16(al, bh[n], acc[m][n], 0, 0, 0);
        }
        __builtin_amdgcn_s_setprio(0);

        if (t < 15) {
            asm volatile("s_waitcnt vmcnt(0)" ::: "memory");
            __builtin_amdgcn_s_barrier();
        }
    }

    float* Cz = C + (long)bz * NN * NN;
    #pragma unroll
    for (int m = 0; m < 8; ++m) {
        const int rb = bm + wr * 128 + m * 16 + ((lane >> 4) << 2);
        #pragma unroll
        for (int n = 0; n < 4; ++n) {
            const int gc = bn + wc * 64 + n * 16 + (lane & 15);
            #pragma unroll
            for (int r = 0; r < 4; ++r) {
                const int gr = rb + r;
                float vv = acc[m][n][r] * scale;
                if (gr == gc) vv += fminf(expf(si[gr]), 3.0f);
                Cz[(long)gr * NN + gc] = vv;
            }
        }
    }
}

// ---------------------------------------------------------------------------
// AV GEMM: 256x128 tile, 8 waves (4x2, 64x64/wave), 16x16 MFMA, K=2048,
// 3-deep buffer ring (3 x 24KB) with counted vmcnt(3) (T4).
// ---------------------------------------------------------------------------
__global__ __launch_bounds__(512, 2) void av_kernel(
    const halfT* __restrict__ P, const halfT* __restrict__ V,
    float* __restrict__ O)
{
    extern __shared__ __align__(16) char smem[];   // 3 bufs x 24576 B

    const int tid  = threadIdx.x;
    const int lane = tid & 63;
    const int w    = tid >> 6;
    const int wr   = w >> 1, wc = w & 1;

    int flat = blockIdx.x;                       // 0..255
    flat = ((flat & 7) << 5) | (flat >> 3);      // batch bz on XCD bz
    const int nx = flat & 3, my = (flat >> 2) & 7, bz = flat >> 5;
    const int bm = my * 256, bn = nx * 128;

    const halfT* A = P + (long)bz * NN * NN;
    const halfT* B = V + (long)bz * DD * NN;

    const int s_row   = w * 16 + (lane >> 2);
    const int s_chunk = (lane & 3) ^ ((lane >> 3) & 3);
    const long gA = (long)(bm + s_row) * NN + s_chunk * 8;
    const long gB = (long)(bn + s_row) * NN + s_chunk * 8;
    const int ldst = w * 1024;
    const long rstep = (long)128 * NN;

    auto stage = [&](char* buf, int t) {
        const long kk = (long)t * 32;
        GLOAD16(A + gA + kk,         buf + ldst);
        GLOAD16(A + gA + rstep + kk, buf + 8192 + ldst);
        GLOAD16(B + gB + kk,         buf + 16384 + ldst);
    };

    const int lr  = lane & 15;
    const int q16 = lane >> 4;
    const int frag = lr * 64 + ((q16 ^ ((lr >> 1) & 3)) << 4);
    const int abase = wr * 4096 + frag;
    const int bbase = wc * 4096 + frag;

    f32x4 acc[4][4];
    #pragma unroll
    for (int m = 0; m < 4; ++m)
        #pragma unroll
        for (int j = 0; j < 4; ++j) acc[m][j] = (f32x4)0.0f;

    stage(smem, 0);
    stage(smem + 24576, 1);
    asm volatile("s_waitcnt vmcnt(3)" ::: "memory");
    __builtin_amdgcn_s_barrier();
    __builtin_amdgcn_sched_barrier(0);

    int cb = 0;
    for (int t = 0; t < 64; ++t) {
        char* cur = smem + (size_t)cb * 24576;
        const int nb = (cb + 2 >= 3) ? cb - 1 : cb + 2;
        if (t < 62) stage(smem + (size_t)nb * 24576, t + 2);

        half8 ah[4], bh[4];
        #pragma unroll
        for (int m = 0; m < 4; ++m)
            ah[m] = *(const half8*)(cur + abase + m * 1024);
        #pragma unroll
        for (int j = 0; j < 4; ++j)
            bh[j] = *(const half8*)(cur + 16384 + bbase + j * 1024);
        __builtin_amdgcn_s_setprio(1);
        #pragma unroll
        for (int m = 0; m < 4; ++m)
            #pragma unroll
            for (int j = 0; j < 4; ++j)
                acc[m][j] = __builtin_amdgcn_mfma_f32_16x16x32_f16(ah[m], bh[j], acc[m][j], 0, 0, 0);
        __builtin_amdgcn_s_setprio(0);

        if (t < 63) {
            if (t < 62) { asm volatile("s_waitcnt vmcnt(3)" ::: "memory"); }
            else        { asm volatile("s_waitcnt vmcnt(0)" ::: "memory"); }
            __builtin_amdgcn_s_barrier();
            __builtin_amdgcn_sched_barrier(0);
        }
        cb = (cb + 1 == 3) ? 0 : cb + 1;
    }

    float* Oz = O + (long)bz * NN * DD;
    #pragma unroll
    for (int m = 0; m < 4; ++m) {
        const int rb = bm + wr * 64 + m * 16 + (q16 << 2);
        #pragma unroll
        for (int j = 0; j < 4; ++j) {
            const int gc = bn + wc * 64 + j * 16 + lr;
            #pragma unroll
            for (int r = 0; r < 4; ++r)
                Oz[(long)(rb + r) * DD + gc] = acc[m][j][r];
        }
    }
}

// ---------------------------------------------------------------------------
// In-place row softmax + entropy partial + fp16 copy of attn.
// ---------------------------------------------------------------------------
__global__ __launch_bounds__(256) void softmax_entropy_kernel(
    float* __restrict__ attn, _Float16* __restrict__ ah, float* __restrict__ partials)
{
    __shared__ float red[4];
    const long row = blockIdx.x;
    float* p = attn + row * (long)NN;
    _Float16* ph = ah + row * (long)NN;
    const int tid = threadIdx.x;
    const int base = tid * 8;

    float4 va = *(const float4*)(p + base);
    float4 vb = *(const float4*)(p + base + 4);
    float v[8] = {va.x, va.y, va.z, va.w, vb.x, vb.y, vb.z, vb.w};

    float m = v[0];
    #pragma unroll
    for (int i = 1; i < 8; ++i) m = fmaxf(m, v[i]);
    #pragma unroll
    for (int o = 32; o; o >>= 1) m = fmaxf(m, __shfl_xor(m, o, 64));
    if ((tid & 63) == 0) red[tid >> 6] = m;
    __syncthreads();
    m = fmaxf(fmaxf(red[0], red[1]), fmaxf(red[2], red[3]));

    float t[8];
    float s = 0.f;
    #pragma unroll
    for (int i = 0; i < 8; ++i) { t[i] = v[i] - m; v[i] = expf(t[i]); s += v[i]; }
    #pragma unroll
    for (int o = 32; o; o >>= 1) s += __shfl_xor(s, o, 64);
    __syncthreads();
    if ((tid & 63) == 0) red[tid >> 6] = s;
    __syncthreads();
    s = red[0] + red[1] + red[2] + red[3];

    const float inv = 1.0f / s;
    const float lns = logf(s);
    float e = 0.f;
    float pv[8];
    #pragma unroll
    for (int i = 0; i < 8; ++i) {
        pv[i] = v[i] * inv;
        e = fmaf(pv[i], t[i] - lns, e);
    }
    *(float4*)(p + base)     = make_float4(pv[0], pv[1], pv[2], pv[3]);
    *(float4*)(p + base + 4) = make_float4(pv[4], pv[5], pv[6], pv[7]);
    half8 h;
    #pragma unroll
    for (int i = 0; i < 8; ++i) h[i] = (_Float16)pv[i];
    *(half8*)(ph + base) = h;

    #pragma unroll
    for (int o = 32; o; o >>= 1) e += __shfl_xor(e, o, 64);
    __syncthreads();
    if ((tid & 63) == 0) red[tid >> 6] = e;
    __syncthreads();
    if (tid == 0) partials[row] = red[0] + red[1] + red[2] + red[3];
}

__global__ __launch_bounds__(256) void ent_reduce_kernel(
    const float* __restrict__ partials, float* __restrict__ ent)
{
    __shared__ float red[4];
    float s = 0.f;
    for (int i = threadIdx.x; i < BB * NN; i += 256) s += partials[i];
    #pragma unroll
    for (int o = 32; o; o >>= 1) s += __shfl_xor(s, o, 64);
    if ((threadIdx.x & 63) == 0) red[threadIdx.x >> 6] = s;
    __syncthreads();
    if (threadIdx.x == 0)
        *ent = -(red[0] + red[1] + red[2] + red[3]) / (float)(BB * NN);
}

extern "C" void kernel_launch(void* const* d_in, const int* in_sizes, int n_in,
                              void* d_out, int out_size, void* d_ws, size_t ws_size,
                              hipStream_t stream) {
    const float* query = (const float*)d_in[0];
    const float* key   = (const float*)d_in[1];
    const float* value = (const float*)d_in[2];
    const float* Wq    = (const float*)d_in[3];
    const float* Wk    = (const float*)d_in[4];
    const float* Wv    = (const float*)d_in[5];
    const float* si    = (const float*)d_in[6];

    float* out  = (float*)d_out;                        // [B,N,D]
    float* attn = out + (size_t)BB * NN * DD;           // [B,N,N]
    float* ent  = attn + (size_t)BB * NN * NN;          // scalar

    const size_t NK = (size_t)BB * NN * DD;             // 8.39M elements
    _Float16* ws16 = (_Float16*)d_ws;
    _Float16* qh = ws16;            // 16.8 MB each
    _Float16* ql = qh + NK;
    _Float16* kh = ql + NK;
    _Float16* kl = kh + NK;
    _Float16* vT = kl + NK;         // vT fp16 [b][512][2048]
    _Float16* WqhT = vT + NK;       // 0.5 MB each
    _Float16* WqlT = WqhT + DD * DD;
    _Float16* WkhT = WqlT + DD * DD;
    _Float16* WklT = WkhT + DD * DD;
    _Float16* WvhT = WklT + DD * DD;
    float* partials = (float*)(WvhT + DD * DD);         // 64 KB
    _Float16* attn_h = ws16;        // 67 MB, aliases qh..kl (dead after scores)

    const dim3 blk(256);
    const float inv_sqrt_d = 0.044194173824159216f;     // 1/sqrt(512)

    wsplit_kernel<<<dim3(8, 8, 3), blk, 0, stream>>>(Wq, Wk, Wv,
        WqhT, WqlT, WkhT, WklT, WvhT);

    // merged q/k/v projections in one launch (768 blocks)
    proj_kernel<<<dim3(768), dim3(512), 98304, stream>>>(
        query, key, value, WqhT, WqlT, WkhT, WklT, WvhT,
        qh, ql, kh, kl, vT);

    // scores = q k^T / sqrt(d) + diag(min(exp(si),3))  [v2 proven]
    scores256_kernel<<<dim3(8, 8, 8), dim3(512), 131072, stream>>>(
        qh, ql, kh, kl, attn, si, inv_sqrt_d);

    softmax_entropy_kernel<<<dim3(BB * NN), blk, 0, stream>>>(attn, attn_h, partials);
    ent_reduce_kernel<<<dim3(1), blk, 0, stream>>>(partials, ent);

    // out = attn @ v  [3-buf counted ring]
    av_kernel<<<dim3(256), dim3(512), 73728, stream>>>(attn_h, vT, out);
}